// Round 1
// baseline (326.493 us; speedup 1.0000x reference)
//
#include <hip/hip_runtime.h>
#include <cstdint>

#define GRIDW   40
#define SEQ     1600      // 40*40
#define NVOCAB  32
#define PATH_ID 6
#define IGNORE_ID (-100)
#define NWORDS  25        // 1600 / 64
#define BLK     256
#define NWAVES  (BLK / 64)

// ---------------------------------------------------------------------------
// One block per batch row.
// Phase 1 (coalesced): 8 lanes cooperate per token. Lane sub=tid&7 loads
// float4 #sub of token i0+(tid>>3), so each wave-level load instruction reads
// 1 KiB fully contiguous (vs the previous 128-B-strided per-lane layout that
// forced 8 temporal touches per cache line and thrashed the 32 KiB L1).
// Argmax / log-sum-exp are finished with 3-level __shfl_xor trees inside the
// 8-lane group; first-occurrence argmax semantics preserved (max-value
// reduce, then min-index among lanes holding the max).
// Phase 2: ballot-packed path bitmap, wave-scan prefix for positions,
// spatial penalty, min-label connected components (__syncthreads_count for
// the convergence test), one atomicAdd per row.
// ---------------------------------------------------------------------------
__global__ __launch_bounds__(BLK) void act_loss_kernel(
    const float* __restrict__ logits,   // [B, SEQ, NVOCAB]
    const int*   __restrict__ labels,   // [B, SEQ]
    const float* __restrict__ qhalt,    // [B]
    float*       __restrict__ out,      // [1]
    int B)
{
    const int b    = blockIdx.x;
    const int tid  = threadIdx.x;
    const int lane = tid & 63;
    const int wid  = tid >> 6;
    const int sub  = tid & 7;        // lane within 8-lane token group

    __shared__ uint8_t  path[SEQ];
    __shared__ uint16_t lab[SEQ];
    __shared__ uint16_t pos[SEQ];
    __shared__ uint64_t words[NWORDS];
    __shared__ int      offs[NWORDS + 1];
    __shared__ int      npath_s;
    __shared__ float    wr_f[NWAVES];
    __shared__ int      wr_i[NWAVES];
    __shared__ int      wr_j[NWAVES];
    __shared__ float    part_a;   // lm + 0.5*bce for this row

    // ---------------- Phase 1: per-token CE / argmax (coalesced) ------------
    float ce_sum = 0.0f;
    int   cnt = 0, cor = 0;

    const float* base  = logits + (size_t)b * SEQ * NVOCAB;
    const int*   lbase = labels + (size_t)b * SEQ;

    const int tokOff = tid >> 3;     // 0..31, token slot within iteration
    for (int i0 = 0; i0 < SEQ; i0 += BLK / 8) {   // 50 iterations, no tail
        const int tok = i0 + tokOff;
        float4 v = ((const float4*)(base + (size_t)tok * NVOCAB))[sub];
        int lbl = lbase[tok];

        // local argmax over this lane's 4 vocab entries (global idx 4*sub+k),
        // ascending scan with strict > keeps first occurrence
        float m = v.x;
        if (v.y > m) m = v.y;
        if (v.z > m) m = v.z;
        if (v.w > m) m = v.w;
        // group max across the 8 lanes
        for (int d = 1; d < 8; d <<= 1)
            m = fmaxf(m, __shfl_xor(m, d));
        // smallest global index attaining the group max (first occurrence)
        int cand = 999;
        if (v.w == m) cand = 4 * sub + 3;
        if (v.z == m) cand = 4 * sub + 2;
        if (v.y == m) cand = 4 * sub + 1;
        if (v.x == m) cand = 4 * sub + 0;
        for (int d = 1; d < 8; d <<= 1)
            cand = min(cand, __shfl_xor(cand, d));

        // sum of exp(x - m) across all 32 entries
        float s = __expf(v.x - m) + __expf(v.y - m)
                + __expf(v.z - m) + __expf(v.w - m);
        for (int d = 1; d < 8; d <<= 1)
            s += __shfl_xor(s, d);

        bool msk  = (lbl != IGNORE_ID);
        int  slbl = (lbl < 0) ? 0 : lbl;
        // x[slbl] lives on lane (slbl>>2) of the group; fetch with one shfl
        int   k2    = slbl & 3;
        float xcand = (k2 == 0) ? v.x : (k2 == 1) ? v.y : (k2 == 2) ? v.z : v.w;
        int   owner = (lane & ~7) | ((slbl >> 2) & 7);
        float xl    = __shfl(xcand, owner);

        if (sub == 0) {
            float lse = m + __logf(s);
            ce_sum += msk ? (lse - xl) : 0.0f;
            cnt    += msk ? 1 : 0;
            cor    += (msk && cand == lbl) ? 1 : 0;
            path[tok] = (cand == PATH_ID) ? 1 : 0;
        }
    }
    __syncthreads();   // path[] complete

    // ---------------- pack path bits -> 25 x uint64 via ballot --------------
    for (int basei = 0; basei < SEQ; basei += BLK) {
        int idx = basei + tid;
        bool p = (idx < SEQ) ? (path[idx] != 0) : false;
        uint64_t w = __ballot(p);
        int widx = (basei >> 6) + wid;
        if (lane == 0 && widx < NWORDS) words[widx] = w;
    }

    // ---------------- block reductions: ce_sum, cnt, cor (shfl trees) -------
    for (int d = 1; d < 64; d <<= 1) {
        ce_sum += __shfl_xor(ce_sum, d);
        cnt    += __shfl_xor(cnt, d);
        cor    += __shfl_xor(cor, d);
    }
    if (lane == 0) { wr_f[wid] = ce_sum; wr_i[wid] = cnt; wr_j[wid] = cor; }
    __syncthreads();   // words[] + wave partials visible

    if (tid == 0) {
        float ce_tot = wr_f[0] + wr_f[1] + wr_f[2] + wr_f[3];
        int   c_tot  = wr_i[0] + wr_i[1] + wr_i[2] + wr_i[3];
        int   k_tot  = wr_j[0] + wr_j[1] + wr_j[2] + wr_j[3];
        float lm = ce_tot / (float)max(c_tot, 1);
        float t  = (k_tot == c_tot) ? 1.0f : 0.0f;
        float xq = qhalt[b];
        float bce = fmaxf(xq, 0.0f) - xq * t + log1pf(expf(-fabsf(xq)));
        part_a = lm + 0.5f * bce;
    }

    // ---------------- offs prefix: wave-0 scan over 25 word popcounts -------
    if (wid == 0) {
        uint64_t w = (lane < NWORDS) ? words[lane] : 0ull;
        int pc = __popcll(w);
        int c = pc;
        for (int d = 1; d < 32; d <<= 1) {
            int t = __shfl_up(c, d);
            if (lane >= d) c += t;
        }
        if (lane < NWORDS) offs[lane] = c - pc;          // exclusive prefix
        if (lane == NWORDS - 1) { offs[NWORDS] = c; npath_s = c; }
    }
    __syncthreads();   // offs/npath_s/part_a visible

    // ---------------- scatter path positions --------------------------------
    if (tid < NWORDS) {
        int o = offs[tid];
        uint64_t w = words[tid];
        int basei = tid * 64;
        while (w) {
            int k = __ffsll((unsigned long long)w) - 1;
            pos[o++] = (uint16_t)(basei + k);
            w &= (w - 1);
        }
    }
    __syncthreads();

    // ---------------- spatial penalty ---------------------------------------
    const int np = npath_s;
    int sp_units = 0;
    for (int q = tid; q + 1 < np; q += BLK) {
        int i = pos[q], j = pos[q + 1];
        int dist = abs(i / GRIDW - j / GRIDW) + abs(i % GRIDW - j % GRIDW);
        if (dist > 1) sp_units += dist - 1;
    }

    // ---------------- connectivity: min-label propagation -------------------
    for (int i = tid; i < SEQ; i += BLK)
        lab[i] = path[i] ? (uint16_t)i : (uint16_t)0xFFFF;
    __syncthreads();

    for (;;) {
        int local = 0;
        for (int i = tid; i < SEQ; i += BLK) {
            if (!path[i]) continue;
            int r = i / GRIDW, c = i % GRIDW;
            uint16_t v = lab[i];
            uint16_t nm = v;
            if (r > 0)         { uint16_t u = lab[i - GRIDW]; nm = (u < nm) ? u : nm; }
            if (r < GRIDW - 1) { uint16_t u = lab[i + GRIDW]; nm = (u < nm) ? u : nm; }
            if (c > 0)         { uint16_t u = lab[i - 1];     nm = (u < nm) ? u : nm; }
            if (c < GRIDW - 1) { uint16_t u = lab[i + 1];     nm = (u < nm) ? u : nm; }
            if (nm < v) { lab[i] = nm; local = 1; }
        }
        if (__syncthreads_count(local) == 0) break;
    }

    int comp = 0;
    for (int i = tid; i < SEQ; i += BLK)
        comp += (path[i] && lab[i] == (uint16_t)i) ? 1 : 0;

    // ---------------- reduce sp_units / comp, emit row contribution ---------
    for (int d = 1; d < 64; d <<= 1) {
        sp_units += __shfl_xor(sp_units, d);
        comp     += __shfl_xor(comp, d);
    }
    if (lane == 0) { wr_i[wid] = sp_units; wr_j[wid] = comp; }
    __syncthreads();

    if (tid == 0) {
        int sp_tot   = wr_i[0] + wr_i[1] + wr_i[2] + wr_i[3];
        int comp_tot = wr_j[0] + wr_j[1] + wr_j[2] + wr_j[3];
        int conn_units = (comp_tot > 1) ? (comp_tot - 1) : 0;
        float total = part_a +
                      ((float)sp_tot * 10.0f + (float)conn_units * 5.0f) / (float)B;
        atomicAdd(out, total);
    }
}

extern "C" void kernel_launch(void* const* d_in, const int* in_sizes, int n_in,
                              void* d_out, int out_size, void* d_ws, size_t ws_size,
                              hipStream_t stream) {
    const float* logits = (const float*)d_in[0];
    const int*   labels = (const int*)d_in[1];
    const float* qhalt  = (const float*)d_in[2];
    // d_in[3] = halted, d_in[4] = steps: metrics-only in reference, unused.
    float* out = (float*)d_out;
    const int B = in_sizes[2];   // q_halt_logits length = batch

    // harness poisons d_out before every launch; we accumulate via atomicAdd,
    // so zero it on-stream first (graph-capture safe).
    hipMemsetAsync(out, 0, (size_t)out_size * sizeof(float), stream);
    act_loss_kernel<<<dim3(B), dim3(BLK), 0, stream>>>(logits, labels, qhalt, out, B);
}

// Round 2
// 307.688 us; speedup vs baseline: 1.0611x; 1.0611x over previous
//
#include <hip/hip_runtime.h>
#include <cstdint>

#define GRIDW   40
#define SEQ     1600      // 40*40
#define NVOCAB  32
#define PATH_ID 6
#define IGNORE_ID (-100)
#define NWORDS  25        // 1600 / 64
#define BLK     256
#define NWAVES  (BLK / 64)
#define TILE_F4 576       // per-wave stage: 64 tokens * 9 float4 (144-B stride)

// ---------------------------------------------------------------------------
// One block per batch row.
// Phase 1 (coalesced + LDS transpose): each wave stages a 64-token tile with
// 8 fully-contiguous 1-KiB global loads (reg-staged), ds_write_b128 into a
// 144-B-stride padded LDS layout (slot = 9*tok + comp -> (l+j)%8 even across
// bank groups, b128-conflict-free), then each lane reads back its OWN token
// (8x ds_read_b128) and runs the per-token argmax/LSE serially in-lane.
// This keeps every global cache line fully consumed by one instruction
// (fixing the round-0 L1 thrash) without round-1's per-token shfl trees.
// Phase 2: ballot-packed path bitmap, wave-scan prefix, spatial penalty,
// min-label connected components, one atomicAdd per row. lab/pos alias the
// (dead) stage buffer to keep LDS <= 39 KB -> 4 blocks/CU.
// ---------------------------------------------------------------------------
__global__ __launch_bounds__(BLK) void act_loss_kernel(
    const float* __restrict__ logits,   // [B, SEQ, NVOCAB]
    const int*   __restrict__ labels,   // [B, SEQ]
    const float* __restrict__ qhalt,    // [B]
    float*       __restrict__ out,      // [1]
    int B)
{
    const int b    = blockIdx.x;
    const int tid  = threadIdx.x;
    const int lane = tid & 63;
    const int wid  = tid >> 6;

    __shared__ __align__(16) float4 stage4[NWAVES * TILE_F4];   // 36864 B
    __shared__ uint8_t  path[SEQ];
    __shared__ uint64_t words[NWORDS];
    __shared__ int      offs[NWORDS + 1];
    __shared__ int      npath_s;
    __shared__ float    wr_f[NWAVES];
    __shared__ int      wr_i[NWAVES];
    __shared__ int      wr_j[NWAVES];
    __shared__ float    part_a;   // lm + 0.5*bce for this row

    // phase-2 aliases into the stage buffer (dead after phase-1 barrier)
    uint16_t* lab = (uint16_t*)stage4;          // 3200 B
    uint16_t* pos = (uint16_t*)stage4 + SEQ;    // next 3200 B

    // ---------------- Phase 1: per-token CE / argmax ------------------------
    float ce_sum = 0.0f;
    int   cnt = 0, cor = 0;

    const float4* gbase = (const float4*)(logits + (size_t)b * SEQ * NVOCAB);
    const int*    lbase = labels + (size_t)b * SEQ;

    float4* stg  = stage4 + wid * TILE_F4;            // this wave's region
    const float* frow_base = (const float*)stg;       // 36-float row stride

    for (int t = wid; t < SEQ / 64; t += NWAVES) {    // 25 tiles, wave-private
        const float4* gp = gbase + (size_t)t * 512;   // 64 tokens * 8 f4

        // 8 fully-coalesced 1-KiB loads into regs
        float4 g[8];
#pragma unroll
        for (int k = 0; k < 8; ++k)
            g[k] = gp[k * 64 + lane];

        int tok = t * 64 + lane;
        int lbl = lbase[tok];                         // coalesced 256 B/wave

        // transpose into padded LDS: token row stride = 9 float4 (144 B)
#pragma unroll
        for (int k = 0; k < 8; ++k)
            stg[(k * 8 + (lane >> 3)) * 9 + (lane & 7)] = g[k];

        // read back own token: slots 9*lane + j -> (lane+j)%8, even groups
        float4 x[8];
#pragma unroll
        for (int j = 0; j < 8; ++j)
            x[j] = stg[lane * 9 + j];

        // argmax, first occurrence (ascending scan, strict >)
        float m = x[0].x; int arg = 0;
#pragma unroll
        for (int j = 0; j < 8; ++j) {
            int i4 = 4 * j;
            if (j > 0 && x[j].x > m) { m = x[j].x; arg = i4; }
            if (x[j].y > m) { m = x[j].y; arg = i4 + 1; }
            if (x[j].z > m) { m = x[j].z; arg = i4 + 2; }
            if (x[j].w > m) { m = x[j].w; arg = i4 + 3; }
        }
        // sum exp(x - m), 4 accumulators for ILP
        float s0 = 0.f, s1 = 0.f, s2 = 0.f, s3 = 0.f;
#pragma unroll
        for (int j = 0; j < 8; ++j) {
            s0 += __expf(x[j].x - m);
            s1 += __expf(x[j].y - m);
            s2 += __expf(x[j].z - m);
            s3 += __expf(x[j].w - m);
        }
        float s = (s0 + s1) + (s2 + s3);

        bool msk  = (lbl != IGNORE_ID);
        int  slbl = (lbl < 0) ? 0 : lbl;
        // the token's row is resident in LDS: one dynamic ds_read_b32
        float xl = frow_base[lane * 36 + slbl];

        float lse = m + __logf(s);
        ce_sum += msk ? (lse - xl) : 0.0f;
        cnt    += msk ? 1 : 0;
        cor    += (msk && arg == lbl) ? 1 : 0;
        path[tok] = (arg == PATH_ID) ? 1 : 0;
    }
    __syncthreads();   // path[] complete; stage buffer now dead -> lab/pos

    // ---------------- pack path bits -> 25 x uint64 via ballot --------------
    for (int basei = 0; basei < SEQ; basei += BLK) {
        int idx = basei + tid;
        bool p = (idx < SEQ) ? (path[idx] != 0) : false;
        uint64_t w = __ballot(p);
        int widx = (basei >> 6) + wid;
        if (lane == 0 && widx < NWORDS) words[widx] = w;
    }

    // ---------------- block reductions: ce_sum, cnt, cor (shfl trees) -------
    for (int d = 1; d < 64; d <<= 1) {
        ce_sum += __shfl_xor(ce_sum, d);
        cnt    += __shfl_xor(cnt, d);
        cor    += __shfl_xor(cor, d);
    }
    if (lane == 0) { wr_f[wid] = ce_sum; wr_i[wid] = cnt; wr_j[wid] = cor; }
    __syncthreads();   // words[] + wave partials visible

    if (tid == 0) {
        float ce_tot = wr_f[0] + wr_f[1] + wr_f[2] + wr_f[3];
        int   c_tot  = wr_i[0] + wr_i[1] + wr_i[2] + wr_i[3];
        int   k_tot  = wr_j[0] + wr_j[1] + wr_j[2] + wr_j[3];
        float lm = ce_tot / (float)max(c_tot, 1);
        float t  = (k_tot == c_tot) ? 1.0f : 0.0f;
        float xq = qhalt[b];
        float bce = fmaxf(xq, 0.0f) - xq * t + log1pf(expf(-fabsf(xq)));
        part_a = lm + 0.5f * bce;
    }

    // ---------------- offs prefix: wave-0 scan over 25 word popcounts -------
    if (wid == 0) {
        uint64_t w = (lane < NWORDS) ? words[lane] : 0ull;
        int pc = __popcll(w);
        int c = pc;
        for (int d = 1; d < 32; d <<= 1) {
            int t = __shfl_up(c, d);
            if (lane >= d) c += t;
        }
        if (lane < NWORDS) offs[lane] = c - pc;          // exclusive prefix
        if (lane == NWORDS - 1) { offs[NWORDS] = c; npath_s = c; }
    }
    __syncthreads();   // offs/npath_s/part_a visible

    // ---------------- scatter path positions --------------------------------
    if (tid < NWORDS) {
        int o = offs[tid];
        uint64_t w = words[tid];
        int basei = tid * 64;
        while (w) {
            int k = __ffsll((unsigned long long)w) - 1;
            pos[o++] = (uint16_t)(basei + k);
            w &= (w - 1);
        }
    }
    __syncthreads();

    // ---------------- spatial penalty ---------------------------------------
    const int np = npath_s;
    int sp_units = 0;
    for (int q = tid; q + 1 < np; q += BLK) {
        int i = pos[q], j = pos[q + 1];
        int dist = abs(i / GRIDW - j / GRIDW) + abs(i % GRIDW - j % GRIDW);
        if (dist > 1) sp_units += dist - 1;
    }

    // ---------------- connectivity: min-label propagation -------------------
    for (int i = tid; i < SEQ; i += BLK)
        lab[i] = path[i] ? (uint16_t)i : (uint16_t)0xFFFF;
    __syncthreads();

    for (;;) {
        int local = 0;
        for (int i = tid; i < SEQ; i += BLK) {
            if (!path[i]) continue;
            int r = i / GRIDW, c = i % GRIDW;
            uint16_t v = lab[i];
            uint16_t nm = v;
            if (r > 0)         { uint16_t u = lab[i - GRIDW]; nm = (u < nm) ? u : nm; }
            if (r < GRIDW - 1) { uint16_t u = lab[i + GRIDW]; nm = (u < nm) ? u : nm; }
            if (c > 0)         { uint16_t u = lab[i - 1];     nm = (u < nm) ? u : nm; }
            if (c < GRIDW - 1) { uint16_t u = lab[i + 1];     nm = (u < nm) ? u : nm; }
            if (nm < v) { lab[i] = nm; local = 1; }
        }
        if (__syncthreads_count(local) == 0) break;
    }

    int comp = 0;
    for (int i = tid; i < SEQ; i += BLK)
        comp += (path[i] && lab[i] == (uint16_t)i) ? 1 : 0;

    // ---------------- reduce sp_units / comp, emit row contribution ---------
    for (int d = 1; d < 64; d <<= 1) {
        sp_units += __shfl_xor(sp_units, d);
        comp     += __shfl_xor(comp, d);
    }
    if (lane == 0) { wr_i[wid] = sp_units; wr_j[wid] = comp; }
    __syncthreads();

    if (tid == 0) {
        int sp_tot   = wr_i[0] + wr_i[1] + wr_i[2] + wr_i[3];
        int comp_tot = wr_j[0] + wr_j[1] + wr_j[2] + wr_j[3];
        int conn_units = (comp_tot > 1) ? (comp_tot - 1) : 0;
        float total = part_a +
                      ((float)sp_tot * 10.0f + (float)conn_units * 5.0f) / (float)B;
        atomicAdd(out, total);
    }
}

extern "C" void kernel_launch(void* const* d_in, const int* in_sizes, int n_in,
                              void* d_out, int out_size, void* d_ws, size_t ws_size,
                              hipStream_t stream) {
    const float* logits = (const float*)d_in[0];
    const int*   labels = (const int*)d_in[1];
    const float* qhalt  = (const float*)d_in[2];
    // d_in[3] = halted, d_in[4] = steps: metrics-only in reference, unused.
    float* out = (float*)d_out;
    const int B = in_sizes[2];   // q_halt_logits length = batch

    // harness poisons d_out before every launch; we accumulate via atomicAdd,
    // so zero it on-stream first (graph-capture safe).
    hipMemsetAsync(out, 0, (size_t)out_size * sizeof(float), stream);
    act_loss_kernel<<<dim3(B), dim3(BLK), 0, stream>>>(logits, labels, qhalt, out, B);
}

// Round 3
// 303.303 us; speedup vs baseline: 1.0765x; 1.0145x over previous
//
#include <hip/hip_runtime.h>
#include <cstdint>

#define GRIDW   40
#define SEQ     1600      // 40*40
#define NVOCAB  32
#define PATH_ID 6
#define IGNORE_ID (-100)
#define NWORDS  25        // 1600 / 64
#define BLK     512
#define NWAVES  (BLK / 64)

// ---------------------------------------------------------------------------
// One block per batch row, 512 threads (8 waves).
// Occupancy experiment: rounds 0/2 both sat at 16 waves/CU (grid- and
// VGPR-limited) and ran identically; this version demands 32 waves/CU
// (1024 blocks x 8 waves) and uses a single-pass ONLINE log-sum-exp
// (running m/arg/s with rescale, per-chunk label select) to cut live
// registers to ~52, with __launch_bounds__(512,8) forcing the <=64-VGPR
// allocation that 8 waves/SIMD requires (m69: occupancy steps at 64/128/256).
// words[] ballot-packing is fused into phase 1 (i>>6 is the word index).
// Phase 2 unchanged in structure: wave-scan prefix, spatial penalty,
// min-label connected components, one atomicAdd per row.
// ---------------------------------------------------------------------------
__global__ __launch_bounds__(BLK, 8) void act_loss_kernel(
    const float* __restrict__ logits,   // [B, SEQ, NVOCAB]
    const int*   __restrict__ labels,   // [B, SEQ]
    const float* __restrict__ qhalt,    // [B]
    float*       __restrict__ out,      // [1]
    int B)
{
    const int b    = blockIdx.x;
    const int tid  = threadIdx.x;
    const int lane = tid & 63;
    const int wid  = tid >> 6;

    __shared__ uint8_t  path[SEQ];
    __shared__ uint16_t lab[SEQ];
    __shared__ uint16_t pos[SEQ];
    __shared__ uint64_t words[NWORDS];
    __shared__ int      offs[NWORDS + 1];
    __shared__ int      npath_s;
    __shared__ float    wr_f[NWAVES];
    __shared__ int      wr_i[NWAVES];
    __shared__ int      wr_j[NWAVES];
    __shared__ float    part_a;   // lm + 0.5*bce for this row

    // ---------------- Phase 1: online CE / argmax, fused word pack ----------
    float ce_sum = 0.0f;
    int   cnt = 0, cor = 0;

    const float* base  = logits + (size_t)b * SEQ * NVOCAB;
    const int*   lbase = labels + (size_t)b * SEQ;

    // online update over one chunk of 8 logits held in two float4s.
    // first chunk (b0==0) initializes; later chunks rescale s on new max.
    // strict > everywhere => first-occurrence argmax preserved.
#define CH(qa, qb, b0)                                                      \
    {                                                                       \
        float cm = qa.x; int ca = (b0);                                     \
        if (qa.y > cm) { cm = qa.y; ca = (b0) + 1; }                        \
        if (qa.z > cm) { cm = qa.z; ca = (b0) + 2; }                        \
        if (qa.w > cm) { cm = qa.w; ca = (b0) + 3; }                        \
        if (qb.x > cm) { cm = qb.x; ca = (b0) + 4; }                        \
        if (qb.y > cm) { cm = qb.y; ca = (b0) + 5; }                        \
        if (qb.z > cm) { cm = qb.z; ca = (b0) + 6; }                        \
        if (qb.w > cm) { cm = qb.w; ca = (b0) + 7; }                        \
        if ((b0) == 0) { m = cm; arg = ca; }                                \
        else if (cm > m) { s *= __expf(m - cm); m = cm; arg = ca; }         \
        s += __expf(qa.x - m) + __expf(qa.y - m)                            \
           + __expf(qa.z - m) + __expf(qa.w - m)                            \
           + __expf(qb.x - m) + __expf(qb.y - m)                            \
           + __expf(qb.z - m) + __expf(qb.w - m);                           \
        if ((slbl >> 3) == ((b0) >> 3)) {                                   \
            int k = slbl & 7;                                               \
            xl = (k == 0) ? qa.x : (k == 1) ? qa.y : (k == 2) ? qa.z :      \
                 (k == 3) ? qa.w : (k == 4) ? qb.x : (k == 5) ? qb.y :      \
                 (k == 6) ? qb.z : qb.w;                                    \
        }                                                                   \
    }

#pragma unroll 1
    for (int i = tid; i < SEQ; i += BLK) {
        const float4* p4 = (const float4*)(base + (size_t)i * NVOCAB);
        float4 q0 = p4[0], q1 = p4[1], q2 = p4[2], q3 = p4[3];
        float4 q4 = p4[4], q5 = p4[5], q6 = p4[6], q7 = p4[7];
        int lbl  = lbase[i];
        int slbl = (lbl < 0) ? 0 : lbl;

        float m, xl = 0.0f, s = 0.0f;
        int   arg;
        CH(q0, q1, 0)
        CH(q2, q3, 8)
        CH(q4, q5, 16)
        CH(q6, q7, 24)

        bool msk = (lbl != IGNORE_ID);
        float lse = m + __logf(s);
        ce_sum += msk ? (lse - xl) : 0.0f;
        cnt    += msk ? 1 : 0;
        cor    += (msk && arg == lbl) ? 1 : 0;

        bool pf = (arg == PATH_ID);
        path[i] = pf ? 1 : 0;
        uint64_t w = __ballot(pf);
        if (lane == 0) words[i >> 6] = w;   // i = it*BLK + wid*64 for lane 0
    }
#undef CH
    __syncthreads();   // path[], words[] complete

    // ---------------- block reductions: ce_sum, cnt, cor (shfl trees) -------
    for (int d = 1; d < 64; d <<= 1) {
        ce_sum += __shfl_xor(ce_sum, d);
        cnt    += __shfl_xor(cnt, d);
        cor    += __shfl_xor(cor, d);
    }
    if (lane == 0) { wr_f[wid] = ce_sum; wr_i[wid] = cnt; wr_j[wid] = cor; }
    __syncthreads();   // wave partials visible

    if (tid == 0) {
        float ce_tot = 0.0f; int c_tot = 0, k_tot = 0;
#pragma unroll
        for (int v = 0; v < NWAVES; ++v) {
            ce_tot += wr_f[v]; c_tot += wr_i[v]; k_tot += wr_j[v];
        }
        float lm = ce_tot / (float)max(c_tot, 1);
        float t  = (k_tot == c_tot) ? 1.0f : 0.0f;
        float xq = qhalt[b];
        float bce = fmaxf(xq, 0.0f) - xq * t + log1pf(expf(-fabsf(xq)));
        part_a = lm + 0.5f * bce;
    }

    // ---------------- offs prefix: wave-0 scan over 25 word popcounts -------
    if (wid == 0) {
        uint64_t w = (lane < NWORDS) ? words[lane] : 0ull;
        int pc = __popcll(w);
        int c = pc;
        for (int d = 1; d < 32; d <<= 1) {
            int t = __shfl_up(c, d);
            if (lane >= d) c += t;
        }
        if (lane < NWORDS) offs[lane] = c - pc;          // exclusive prefix
        if (lane == NWORDS - 1) { offs[NWORDS] = c; npath_s = c; }
    }
    __syncthreads();   // offs/npath_s/part_a visible

    // ---------------- scatter path positions + init labels ------------------
    for (int i = tid; i < SEQ; i += BLK)
        lab[i] = path[i] ? (uint16_t)i : (uint16_t)0xFFFF;
    if (tid < NWORDS) {
        int o = offs[tid];
        uint64_t w = words[tid];
        int basei = tid * 64;
        while (w) {
            int k = __ffsll((unsigned long long)w) - 1;
            pos[o++] = (uint16_t)(basei + k);
            w &= (w - 1);
        }
    }
    __syncthreads();

    // ---------------- spatial penalty ---------------------------------------
    const int np = npath_s;
    int sp_units = 0;
    for (int q = tid; q + 1 < np; q += BLK) {
        int i = pos[q], j = pos[q + 1];
        int dist = abs(i / GRIDW - j / GRIDW) + abs(i % GRIDW - j % GRIDW);
        if (dist > 1) sp_units += dist - 1;
    }

    // ---------------- connectivity: min-label propagation -------------------
    for (;;) {
        int local = 0;
        for (int i = tid; i < SEQ; i += BLK) {
            if (!path[i]) continue;
            int r = i / GRIDW, c = i % GRIDW;
            uint16_t v = lab[i];
            uint16_t nm = v;
            if (r > 0)         { uint16_t u = lab[i - GRIDW]; nm = (u < nm) ? u : nm; }
            if (r < GRIDW - 1) { uint16_t u = lab[i + GRIDW]; nm = (u < nm) ? u : nm; }
            if (c > 0)         { uint16_t u = lab[i - 1];     nm = (u < nm) ? u : nm; }
            if (c < GRIDW - 1) { uint16_t u = lab[i + 1];     nm = (u < nm) ? u : nm; }
            if (nm < v) { lab[i] = nm; local = 1; }
        }
        if (__syncthreads_count(local) == 0) break;
    }

    int comp = 0;
    for (int i = tid; i < SEQ; i += BLK)
        comp += (path[i] && lab[i] == (uint16_t)i) ? 1 : 0;

    // ---------------- reduce sp_units / comp, emit row contribution ---------
    for (int d = 1; d < 64; d <<= 1) {
        sp_units += __shfl_xor(sp_units, d);
        comp     += __shfl_xor(comp, d);
    }
    if (lane == 0) { wr_i[wid] = sp_units; wr_j[wid] = comp; }
    __syncthreads();

    if (tid == 0) {
        int sp_tot = 0, comp_tot = 0;
#pragma unroll
        for (int v = 0; v < NWAVES; ++v) { sp_tot += wr_i[v]; comp_tot += wr_j[v]; }
        int conn_units = (comp_tot > 1) ? (comp_tot - 1) : 0;
        float total = part_a +
                      ((float)sp_tot * 10.0f + (float)conn_units * 5.0f) / (float)B;
        atomicAdd(out, total);
    }
}

extern "C" void kernel_launch(void* const* d_in, const int* in_sizes, int n_in,
                              void* d_out, int out_size, void* d_ws, size_t ws_size,
                              hipStream_t stream) {
    const float* logits = (const float*)d_in[0];
    const int*   labels = (const int*)d_in[1];
    const float* qhalt  = (const float*)d_in[2];
    // d_in[3] = halted, d_in[4] = steps: metrics-only in reference, unused.
    float* out = (float*)d_out;
    const int B = in_sizes[2];   // q_halt_logits length = batch

    // harness poisons d_out before every launch; we accumulate via atomicAdd,
    // so zero it on-stream first (graph-capture safe).
    hipMemsetAsync(out, 0, (size_t)out_size * sizeof(float), stream);
    act_loss_kernel<<<dim3(B), dim3(BLK), 0, stream>>>(logits, labels, qhalt, out, B);
}